// Round 3
// baseline (151.068 us; speedup 1.0000x reference)
//
#include <hip/hip_runtime.h>

#define N 8192
#define M 4
#define L 256
#define THREADS 256

#define CBLK 2048         // cox blocks (4 rows each)
#define KBLK 2048         // kl blocks
#define ROWS 4

// ws float layout
#define WS_TIME 0                      // [0 .. N)            packed times
#define WS_EXPH N                      // [N .. N+5N)         exph[s][j], s=0 joint, 1..4 modality
#define WS_CP   (6 * N)                // [.. +5*CBLK)        cox partials [5][CBLK]
#define WS_KP   (6 * N + 5 * CBLK)     // [.. +2*KBLK)        kl partials  [2][KBLK]

__device__ __forceinline__ float waveSum(float v) {
#pragma unroll
    for (int off = 32; off > 0; off >>= 1) v += __shfl_down(v, off, 64);
    return v;
}

__device__ __forceinline__ float kl4(float4 l, float4 s) {
    float k;
    k  = 0.5f * (s.x * s.x + l.x * l.x) - __logf(s.x) - 0.5f;
    k += 0.5f * (s.y * s.y + l.y * l.y) - __logf(s.y) - 0.5f;
    k += 0.5f * (s.z * s.z + l.z * l.z) - __logf(s.z) - 0.5f;
    k += 0.5f * (s.w * s.w + l.w * l.w) - __logf(s.w) - 0.5f;
    return k;
}

// ---- k0: pack time, exp(hazards) once ----
__global__ __launch_bounds__(THREADS) void prep_kernel(
    const float* __restrict__ jlh, const float* __restrict__ mlh,
    const float* __restrict__ target, float* __restrict__ ws)
{
    const int tid = blockIdx.x * blockDim.x + threadIdx.x;
    const int nth = gridDim.x * blockDim.x;
    for (int i = tid; i < 5 * N; i += nth) {
        const float h = (i < N) ? jlh[i] : mlh[i - N];
        ws[WS_EXPH + i] = __expf(h);
    }
    for (int i = tid; i < N; i += nth) ws[WS_TIME + i] = target[2 * i];
}

// ---- k1: fused cox + kl ----
__global__ __launch_bounds__(THREADS) void fused_kernel(
    const float* __restrict__ jlh, const float* __restrict__ mlh,
    const float4* __restrict__ jloc4, const float4* __restrict__ jscale4,
    const float4* __restrict__ mloc4, const float4* __restrict__ mscale4,
    const float* __restrict__ target, float* __restrict__ ws)
{
    const int tid = threadIdx.x;

    if ((blockIdx.x & 1) == 0) {
        // ---------------- Cox path: 4 rows, full j sweep ----------------
        const int c  = blockIdx.x >> 1;        // 0..CBLK-1
        const int i0 = c * ROWS;

        const float4* tv = (const float4*)(ws + WS_TIME);
        const float4* e0 = (const float4*)(ws + WS_EXPH);
        const float4* e1 = (const float4*)(ws + WS_EXPH + N);
        const float4* e2 = (const float4*)(ws + WS_EXPH + 2 * N);
        const float4* e3 = (const float4*)(ws + WS_EXPH + 3 * N);
        const float4* e4 = (const float4*)(ws + WS_EXPH + 4 * N);

        float t_i[ROWS];
#pragma unroll
        for (int r = 0; r < ROWS; ++r) t_i[r] = target[2 * (i0 + r)];

        float acc[ROWS][5];
#pragma unroll
        for (int r = 0; r < ROWS; ++r)
#pragma unroll
            for (int s = 0; s < 5; ++s) acc[r][s] = 0.f;

#pragma unroll 2
        for (int g = 0; g < N / (THREADS * 4); ++g) {
            const int q = g * THREADS + tid;
            const float4 tj = tv[q];
            const float4 x0 = e0[q];
            const float4 x1 = e1[q];
            const float4 x2 = e2[q];
            const float4 x3 = e3[q];
            const float4 x4 = e4[q];
#pragma unroll
            for (int r = 0; r < ROWS; ++r) {
                const float ti = t_i[r];
                const float m0 = (tj.x >= ti) ? 1.f : 0.f;
                const float m1 = (tj.y >= ti) ? 1.f : 0.f;
                const float m2 = (tj.z >= ti) ? 1.f : 0.f;
                const float m3 = (tj.w >= ti) ? 1.f : 0.f;
                acc[r][0] = fmaf(m0, x0.x, fmaf(m1, x0.y, fmaf(m2, x0.z, fmaf(m3, x0.w, acc[r][0]))));
                acc[r][1] = fmaf(m0, x1.x, fmaf(m1, x1.y, fmaf(m2, x1.z, fmaf(m3, x1.w, acc[r][1]))));
                acc[r][2] = fmaf(m0, x2.x, fmaf(m1, x2.y, fmaf(m2, x2.z, fmaf(m3, x2.w, acc[r][2]))));
                acc[r][3] = fmaf(m0, x3.x, fmaf(m1, x3.y, fmaf(m2, x3.z, fmaf(m3, x3.w, acc[r][3]))));
                acc[r][4] = fmaf(m0, x4.x, fmaf(m1, x4.y, fmaf(m2, x4.z, fmaf(m3, x4.w, acc[r][4]))));
            }
        }

#pragma unroll
        for (int r = 0; r < ROWS; ++r)
#pragma unroll
            for (int s = 0; s < 5; ++s) acc[r][s] = waveSum(acc[r][s]);

        __shared__ float red[4][ROWS][5];
        __shared__ float cr[ROWS][5];
        const int lane = tid & 63, wid = tid >> 6;
        if (lane == 0) {
#pragma unroll
            for (int r = 0; r < ROWS; ++r)
#pragma unroll
                for (int s = 0; s < 5; ++s) red[wid][r][s] = acc[r][s];
        }
        __syncthreads();

        if (tid < ROWS * 5) {
            const int r = tid / 5, s = tid % 5;
            const float risk = red[0][r][s] + red[1][r][s] + red[2][r][s] + red[3][r][s];
            const float ev = target[2 * (i0 + r) + 1];
            const float h = (s == 0) ? jlh[i0 + r] : mlh[(s - 1) * N + i0 + r];
            cr[r][s] = ev * (h - __logf(risk));
        }
        __syncthreads();

        if (tid < 5) {
            float v = 0.f;
#pragma unroll
            for (int r = 0; r < ROWS; ++r) v += cr[r][tid];
            ws[WS_CP + tid * CBLK + c] = v;
        }
    } else {
        // ---------------- KL path: pure streaming ----------------
        const int k = blockIdx.x >> 1;         // 0..KBLK-1
        float kj, km = 0.f;
        {
            const int idx = k * THREADS + tid;             // joint: 1 f4/thread
            kj = kl4(jloc4[idx], jscale4[idx]);
        }
#pragma unroll
        for (int it = 0; it < 4; ++it) {                   // modality: 4 f4/thread
            const int idx = k * (4 * THREADS) + it * THREADS + tid;
            km += kl4(mloc4[idx], mscale4[idx]);
        }
        kj = waveSum(kj);
        km = waveSum(km);
        __shared__ float kred[2][4];
        const int lane = tid & 63, wid = tid >> 6;
        if (lane == 0) { kred[0][wid] = kj; kred[1][wid] = km; }
        __syncthreads();
        if (tid == 0)
            ws[WS_KP + k] = kred[0][0] + kred[0][1] + kred[0][2] + kred[0][3];
        if (tid == 1)
            ws[WS_KP + KBLK + k] = kred[1][0] + kred[1][1] + kred[1][2] + kred[1][3];
    }
}

// ---- k2: final reduction ----
__global__ __launch_bounds__(THREADS) void finalize_kernel(
    const float* __restrict__ target, const float* __restrict__ ws,
    const float* __restrict__ alpha_p, const float* __restrict__ beta_p,
    float* __restrict__ out)
{
    const int tid = threadIdx.x;
    float ev = 0.f;
    for (int i = tid; i < N; i += THREADS) ev += target[2 * i + 1];
    float s0 = 0.f, s1 = 0.f, s2 = 0.f, s3 = 0.f, s4 = 0.f, kj = 0.f, km = 0.f;
    for (int i = tid; i < CBLK; i += THREADS) {
        s0 += ws[WS_CP + 0 * CBLK + i];
        s1 += ws[WS_CP + 1 * CBLK + i];
        s2 += ws[WS_CP + 2 * CBLK + i];
        s3 += ws[WS_CP + 3 * CBLK + i];
        s4 += ws[WS_CP + 4 * CBLK + i];
        kj += ws[WS_KP + i];
        km += ws[WS_KP + KBLK + i];
    }
    ev = waveSum(ev); s0 = waveSum(s0); s1 = waveSum(s1); s2 = waveSum(s2);
    s3 = waveSum(s3); s4 = waveSum(s4); kj = waveSum(kj); km = waveSum(km);

    __shared__ float red[8][4];
    const int lane = tid & 63, wid = tid >> 6;
    if (lane == 0) {
        red[0][wid] = ev; red[1][wid] = s0; red[2][wid] = s1; red[3][wid] = s2;
        red[4][wid] = s3; red[5][wid] = s4; red[6][wid] = kj; red[7][wid] = km;
    }
    __syncthreads();
    if (tid == 0) {
        float v[8];
#pragma unroll
        for (int q = 0; q < 8; ++q) v[q] = red[q][0] + red[q][1] + red[q][2] + red[q][3];
        const float EV = v[0];
        const float alpha = alpha_p[0], beta = beta_p[0];
        const float cox_j = -v[1] / EV;
        const float cox_m = -(v[2] + v[3] + v[4] + v[5]) / EV;
        out[0] = cox_j + beta * (v[6] / (float)N) + alpha * (cox_m + beta * (v[7] / (float)N));
    }
}

extern "C" void kernel_launch(void* const* d_in, const int* in_sizes, int n_in,
                              void* d_out, int out_size, void* d_ws, size_t ws_size,
                              hipStream_t stream) {
    const float* jlh    = (const float*)d_in[0];  // (N,)
    const float* mlh    = (const float*)d_in[1];  // (M,N)
    const float* jloc   = (const float*)d_in[2];  // (N,L)
    const float* jscale = (const float*)d_in[3];  // (N,L)
    const float* mloc   = (const float*)d_in[4];  // (M,N,L)
    const float* mscale = (const float*)d_in[5];  // (M,N,L)
    const float* target = (const float*)d_in[6];  // (N,2)
    const float* alpha  = (const float*)d_in[7];
    const float* beta   = (const float*)d_in[8];
    float* out = (float*)d_out;
    float* ws  = (float*)d_ws;

    prep_kernel<<<64, THREADS, 0, stream>>>(jlh, mlh, target, ws);

    fused_kernel<<<CBLK + KBLK, THREADS, 0, stream>>>(
        jlh, mlh, (const float4*)jloc, (const float4*)jscale,
        (const float4*)mloc, (const float4*)mscale, target, ws);

    finalize_kernel<<<1, THREADS, 0, stream>>>(target, ws, alpha, beta, out);
}